// Round 16
// baseline (419.338 us; speedup 1.0000x reference)
//
#include <hip/hip_runtime.h>
#include <math.h>

#define THREADS  256
#define NPTS     8192
#define BATCH    8
#define ENTRIES  (2 * BATCH * NPTS)               // 131072 per-query slots
#define ENC_U4   (2 * BATCH * 8 * 2048)           // 262144 uint4 = 4 MB
#define ENC_BYTES ((size_t)ENC_U4 * 16)
#define NPLANES  4
#define MINS_BYTES ((size_t)NPLANES * ENTRIES * 4) // 2 MB
#define WS1_BYTES (ENC_BYTES + MINS_BYTES)         // 6 MB tier-1
#define WS_BYTES  ((size_t)ENTRIES * 4)            // 512 KB tier-2

typedef __attribute__((ext_vector_type(8)))  short bf16x8;
typedef __attribute__((ext_vector_type(8)))  float f32x8;
typedef __attribute__((ext_vector_type(16))) float f32x16;

union FragCast { uint4 u; bf16x8 v; };

__device__ __forceinline__ unsigned short f2bf(float f) {
    unsigned u = __float_as_uint(f);
    unsigned r = (u + 0x7FFFu + ((u >> 16) & 1u)) >> 16;   // RNE
    return (unsigned short)r;
}
__device__ __forceinline__ float bf2f(unsigned short h) {
    return __uint_as_float(((unsigned)h) << 16);
}
#define PK(a, b) (((unsigned)(a)) | (((unsigned)(b)) << 16))
#define BF_ONE 0x3F80u

// ---------- encode a point (x,y,z) into the two 16B K-half rows ----------
__device__ __forceinline__ void encode_db_point(float x, float y, float z,
                                                uint4& h0, uint4& h1) {
    const float sq = fmaf(x, x, fmaf(y, y, z * z));
    const unsigned short xh = f2bf(x), yh = f2bf(y), zh = f2bf(z);
    const unsigned short xl = f2bf(x - bf2f(xh));
    const unsigned short yl = f2bf(y - bf2f(yh));
    const unsigned short zl = f2bf(z - bf2f(zh));
    const unsigned short sh = f2bf(sq);
    const unsigned short sl = f2bf(sq - bf2f(sh));
    h0 = make_uint4(PK(xh, yh), PK(zh, xl), PK(yl, zl), PK(xh, yh));
    h1 = make_uint4(PK(zh, xl), PK(yl, zl), PK(sh, sl), PK(BF_ONE, BF_ONE));
}

// ---------- build a query B-fragment (w = -2q, |q|^2 in k-slots) ----------
__device__ __forceinline__ bf16x8 make_query_frag(const float* qp, int half) {
    const float x = qp[0], y = qp[1], z = qp[2];
    const float sq = fmaf(x, x, fmaf(y, y, z * z));
    const float wx = -2.0f * x, wy = -2.0f * y, wz = -2.0f * z;
    const unsigned short wxh = f2bf(wx), wyh = f2bf(wy), wzh = f2bf(wz);
    const unsigned short wxl = f2bf(wx - bf2f(wxh));
    const unsigned short wyl = f2bf(wy - bf2f(wyh));
    const unsigned short wzl = f2bf(wz - bf2f(wzh));
    const unsigned short sh  = f2bf(sq);
    const unsigned short sl  = f2bf(sq - bf2f(sh));
    FragCast fc;
    if (half == 0) fc.u = make_uint4(PK(wxh, wyh), PK(wzh, wxh), PK(wyh, wzh), PK(wxl, wyl));
    else           fc.u = make_uint4(PK(wzl, wxl), PK(wyl, wzl), PK(BF_ONE, BF_ONE), PK(sh, sl));
    return fc.v;
}

// ================= tier-1a: pre-encode both arrays (A-frag image) =================
__global__ __launch_bounds__(THREADS)
void chamfer_encode_kernel(const float* __restrict__ pred,
                           const float* __restrict__ target,
                           uint4* __restrict__ enc,
                           float* __restrict__ out)
{
    const int t   = blockIdx.x * THREADS + threadIdx.x;   // 0..131071
    if (t == 0) out[0] = 0.0f;
    const int arr = t >> 16;
    const int rem = t & 0xFFFF;
    const int b   = rem >> 13;
    const int p   = rem & (NPTS - 1);
    const float* src = (arr ? target : pred) + ((size_t)b * NPTS + p) * 3;
    uint4 h0, h1;
    encode_db_point(src[0], src[1], src[2], h0, h1);
    const int T = p >> 5, c = p & 31;
    uint4* base = enc + (size_t)(arr * BATCH + b) * 16384;
    base[T * 64 + c]      = h0;
    base[T * 64 + c + 32] = h1;
}

// ================= tier-1b: MFMA min kernel — ping/pong A-prefetch =================
// grid bits: ds(2) | qb(4) | b(3) | dir(1) -> 1024 blocks, 4 waves, 4 blk/CU.
// R15 was load-latency-serialized (~1500 cyc/tile, ~1 load in flight). Fix:
// 2-tile groups with NAMED ping/pong buffers (no runtime-indexed arrays ->
// no scratch); next group's loads issue BEFORE current group's 8 MFMA + 64
// min3, hiding ~500 cyc L3 latency under >1000 cyc of compute per cohort.
__global__ __launch_bounds__(THREADS, 4)
void chamfer_mfma4_kernel(const float* __restrict__ pred,
                          const float* __restrict__ target,
                          const uint4* __restrict__ enc,
                          float* __restrict__ mins)
{
    const int bx  = blockIdx.x;
    const int ds  = bx & 3;
    const int qb  = (bx >> 2) & 15;
    const int b   = (bx >> 6) & 7;
    const int dir = bx >> 9;

    const float* qarr = dir ? target : pred;
    const int arr_db  = dir ^ 1;

    const int tid  = threadIdx.x;
    const int ln   = tid & 63;
    const int w    = tid >> 6;
    const int half = ln >> 5;

    // ---- 4 query B-fragments (128 queries/wave) ----
    const int qbase = qb * 512 + w * 128;
    const size_t qrow = (size_t)b * NPTS;
    bf16x8 bq0 = make_query_frag(qarr + (qrow + qbase +  0 + (ln & 31)) * 3, half);
    bf16x8 bq1 = make_query_frag(qarr + (qrow + qbase + 32 + (ln & 31)) * 3, half);
    bf16x8 bq2 = make_query_frag(qarr + (qrow + qbase + 64 + (ln & 31)) * 3, half);
    bf16x8 bq3 = make_query_frag(qarr + (qrow + qbase + 96 + (ln & 31)) * 3, half);

    const f32x16 zacc = {};
    f32x8 m0, m1, m2, m3;
    #pragma unroll
    for (int i = 0; i < 8; ++i) { m0[i] = INFINITY; m1[i] = INFINITY; m2[i] = INFINITY; m3[i] = INFINITY; }

    const uint4* gb = enc + (size_t)(arr_db * BATCH + b) * 16384 + ds * 4096 + ln;

    FragCast ca0, ca1, pa0, pa1;

    // COMPUTE on a 2-tile group: 8 MFMA + 64 min3
#define CHAMFER_COMPUTE(X0, X1)                                                          \
    {                                                                                    \
        const f32x16 c00 = __builtin_amdgcn_mfma_f32_32x32x16_bf16(X0.v, bq0, zacc, 0, 0, 0); \
        const f32x16 c01 = __builtin_amdgcn_mfma_f32_32x32x16_bf16(X1.v, bq0, zacc, 0, 0, 0); \
        _Pragma("unroll")                                                                \
        for (int i = 0; i < 8; ++i) m0[i] = fminf(fminf(m0[i], fminf(c00[2*i], c00[2*i+1])), fminf(c01[2*i], c01[2*i+1])); \
        const f32x16 c10 = __builtin_amdgcn_mfma_f32_32x32x16_bf16(X0.v, bq1, zacc, 0, 0, 0); \
        const f32x16 c11 = __builtin_amdgcn_mfma_f32_32x32x16_bf16(X1.v, bq1, zacc, 0, 0, 0); \
        _Pragma("unroll")                                                                \
        for (int i = 0; i < 8; ++i) m1[i] = fminf(fminf(m1[i], fminf(c10[2*i], c10[2*i+1])), fminf(c11[2*i], c11[2*i+1])); \
        const f32x16 c20 = __builtin_amdgcn_mfma_f32_32x32x16_bf16(X0.v, bq2, zacc, 0, 0, 0); \
        const f32x16 c21 = __builtin_amdgcn_mfma_f32_32x32x16_bf16(X1.v, bq2, zacc, 0, 0, 0); \
        _Pragma("unroll")                                                                \
        for (int i = 0; i < 8; ++i) m2[i] = fminf(fminf(m2[i], fminf(c20[2*i], c20[2*i+1])), fminf(c21[2*i], c21[2*i+1])); \
        const f32x16 c30 = __builtin_amdgcn_mfma_f32_32x32x16_bf16(X0.v, bq3, zacc, 0, 0, 0); \
        const f32x16 c31 = __builtin_amdgcn_mfma_f32_32x32x16_bf16(X1.v, bq3, zacc, 0, 0, 0); \
        _Pragma("unroll")                                                                \
        for (int i = 0; i < 8; ++i) m3[i] = fminf(fminf(m3[i], fminf(c30[2*i], c30[2*i+1])), fminf(c31[2*i], c31[2*i+1])); \
    }

    // prologue: tiles 0,1 into ca
    ca0.u = gb[0 * 64];
    ca1.u = gb[1 * 64];

    for (int j2 = 0; j2 < 64; j2 += 4) {
        // prefetch tiles j2+2, j2+3 into pa; compute ca (tiles j2, j2+1)
        if (j2 + 2 < 64) { pa0.u = gb[(j2 + 2) * 64]; pa1.u = gb[(j2 + 3) * 64]; }
        CHAMFER_COMPUTE(ca0, ca1);
        // prefetch tiles j2+4, j2+5 into ca; compute pa (tiles j2+2, j2+3)
        if (j2 + 4 < 64) { ca0.u = gb[(j2 + 4) * 64]; ca1.u = gb[(j2 + 5) * 64]; }
        CHAMFER_COMPUTE(pa0, pa1);
    }
#undef CHAMFER_COMPUTE

    // ---- fold 8 -> 1 per frag, cross-half, store to ds-plane ----
    const int base = ds * ENTRIES + dir * (BATCH * NPTS) + b * NPTS + qbase;
    #pragma unroll
    for (int nb = 0; nb < 4; ++nb) {
        const f32x8& m = (nb == 0) ? m0 : (nb == 1) ? m1 : (nb == 2) ? m2 : m3;
        float r = fminf(fminf(fminf(m[0], m[1]), fminf(m[2], m[3])),
                        fminf(fminf(m[4], m[5]), fminf(m[6], m[7])));
        r = fminf(r, __shfl_xor(r, 32, 64));
        if (ln < 32) mins[base + nb * 32 + ln] = r;
    }
}

// ---- tier-1c finish: 128 blocks, min 4 planes, clamp, sum, atomicAdd ----
__global__ __launch_bounds__(THREADS)
void chamfer_finish4_kernel(const float* __restrict__ mins,
                            float* __restrict__ out,
                            float inv_count)
{
    const int t = blockIdx.x * THREADS + threadIdx.x;     // 0..32767
    const float4* p0 = (const float4*)mins;
    const float4* p1 = (const float4*)(mins + ENTRIES);
    const float4* p2 = (const float4*)(mins + 2 * ENTRIES);
    const float4* p3 = (const float4*)(mins + 3 * ENTRIES);
    const float4 a = p0[t], c = p1[t], d = p2[t], e = p3[t];
    float s = fmaxf(fminf(fminf(a.x, c.x), fminf(d.x, e.x)), 0.0f)
            + fmaxf(fminf(fminf(a.y, c.y), fminf(d.y, e.y)), 0.0f)
            + fmaxf(fminf(fminf(a.z, c.z), fminf(d.z, e.z)), 0.0f)
            + fmaxf(fminf(fminf(a.w, c.w), fminf(d.w, e.w)), 0.0f);
    float v = s;
    #pragma unroll
    for (int off = 32; off > 0; off >>= 1)
        v += __shfl_down(v, off, 64);
    __shared__ float wsum[THREADS / 64];
    if ((threadIdx.x & 63) == 0) wsum[threadIdx.x >> 6] = v;
    __syncthreads();
    if (threadIdx.x == 0)
        atomicAdd(out, (wsum[0] + wsum[1] + wsum[2] + wsum[3]) * inv_count);
}

// ================= tier-2: atomic-key kernels (ws in [512K, 6M)) =================
__global__ __launch_bounds__(THREADS, 4)
void chamfer_mfma_kernel(const float* __restrict__ pred,
                         const float* __restrict__ target,
                         unsigned* __restrict__ wskeys)
{
    __shared__ short lds[32 * 64 * 8];
    const int bx  = blockIdx.x;
    const int ds  = bx & 3;
    const int qb  = (bx >> 2) & 15;
    const int b   = (bx >> 6) & 7;
    const int dir = bx >> 9;
    const float* qarr = dir ? target : pred;
    const float* darr = dir ? pred   : target;
    const int tid  = threadIdx.x;
    const int ln   = tid & 63;
    const int w    = tid >> 6;
    const int half = ln >> 5;

    bf16x8 bq[4];
    const int qbase = qb * 512 + w * 128;
    #pragma unroll
    for (int nb = 0; nb < 4; ++nb)
        bq[nb] = make_query_frag(qarr + ((size_t)b * NPTS + qbase + nb * 32 + (ln & 31)) * 3, half);

    float mn[4] = {INFINITY, INFINITY, INFINITY, INFINITY};
    const int range0 = ds * 2048;
    for (int chunk = 0; chunk < 2; ++chunk) {
        #pragma unroll
        for (int it = 0; it < 4; ++it) {
            const int pl = it * THREADS + tid;
            const int p  = range0 + chunk * 1024 + pl;
            const float* tp = darr + ((size_t)b * NPTS + p) * 3;
            uint4 h0, h1;
            encode_db_point(tp[0], tp[1], tp[2], h0, h1);
            const int j = pl >> 5, c = pl & 31;
            *(uint4*)&lds[(j * 64 + c) * 8]      = h0;
            *(uint4*)&lds[(j * 64 + c + 32) * 8] = h1;
        }
        __syncthreads();
        #pragma unroll 4
        for (int j = 0; j < 32; ++j) {
            const bf16x8 a = *(const bf16x8*)&lds[(j * 64 + ln) * 8];
            f32x16 z = {};
            f32x16 c0 = __builtin_amdgcn_mfma_f32_32x32x16_bf16(a, bq[0], z, 0, 0, 0);
            f32x16 c1 = __builtin_amdgcn_mfma_f32_32x32x16_bf16(a, bq[1], z, 0, 0, 0);
            f32x16 c2 = __builtin_amdgcn_mfma_f32_32x32x16_bf16(a, bq[2], z, 0, 0, 0);
            f32x16 c3 = __builtin_amdgcn_mfma_f32_32x32x16_bf16(a, bq[3], z, 0, 0, 0);
            #pragma unroll
            for (int i = 0; i < 16; i += 2) {
                mn[0] = fminf(mn[0], fminf(c0[i], c0[i + 1]));
                mn[1] = fminf(mn[1], fminf(c1[i], c1[i + 1]));
                mn[2] = fminf(mn[2], fminf(c2[i], c2[i + 1]));
                mn[3] = fminf(mn[3], fminf(c3[i], c3[i + 1]));
            }
        }
        __syncthreads();
    }
    const int obase = dir * (BATCH * NPTS) + b * NPTS;
    #pragma unroll
    for (int nb = 0; nb < 4; ++nb) {
        const float o = __shfl_xor(mn[nb], 32, 64);
        const float m = fminf(mn[nb], o);
        if (ln < 32) {
            const unsigned u   = __float_as_uint(m);
            const unsigned key = (u >> 31) ? ~u : (u | 0x80000000u);
            atomicMin(&wskeys[obase + qbase + nb * 32 + ln], key);
        }
    }
}

__global__ __launch_bounds__(THREADS)
void chamfer_finish_kernel(const unsigned* __restrict__ ws,
                           float* __restrict__ out,
                           float inv_count)
{
    const int t = blockIdx.x * THREADS + threadIdx.x;
    const uint4 kk = ((const uint4*)ws)[t];
    float s = 0.0f;
    { const unsigned u = (kk.x >> 31) ? (kk.x ^ 0x80000000u) : ~kk.x; s += fmaxf(__uint_as_float(u), 0.0f); }
    { const unsigned u = (kk.y >> 31) ? (kk.y ^ 0x80000000u) : ~kk.y; s += fmaxf(__uint_as_float(u), 0.0f); }
    { const unsigned u = (kk.z >> 31) ? (kk.z ^ 0x80000000u) : ~kk.z; s += fmaxf(__uint_as_float(u), 0.0f); }
    { const unsigned u = (kk.w >> 31) ? (kk.w ^ 0x80000000u) : ~kk.w; s += fmaxf(__uint_as_float(u), 0.0f); }
    float v = s;
    #pragma unroll
    for (int off = 32; off > 0; off >>= 1)
        v += __shfl_down(v, off, 64);
    __shared__ float wsum[THREADS / 64];
    if ((threadIdx.x & 63) == 0) wsum[threadIdx.x >> 6] = v;
    __syncthreads();
    if (threadIdx.x == 0)
        atomicAdd(out, (wsum[0] + wsum[1] + wsum[2] + wsum[3]) * inv_count);
}

// ================= tier-3 fallback =================
__global__ __launch_bounds__(THREADS, 2)
void chamfer_fallback_kernel(const float* __restrict__ pred,
                             const float* __restrict__ target,
                             float* __restrict__ out,
                             float inv_count)
{
    __shared__ float4 lds[2048];
    const float* q  = (blockIdx.y == 0) ? pred   : target;
    const float* db = (blockIdx.y == 0) ? target : pred;
    const int b = blockIdx.x / (NPTS / THREADS);
    const int n = (blockIdx.x % (NPTS / THREADS)) * THREADS + threadIdx.x;
    const float* qp = q + ((size_t)b * NPTS + n) * 3;
    const float px = qp[0], py = qp[1], pz = qp[2];
    const float npx = -2.0f * px, npy = -2.0f * py, npz = -2.0f * pz;
    const float P = px * px + py * py + pz * pz;
    const float* dbB = db + (size_t)b * NPTS * 3;
    float m0 = INFINITY;
    for (int c0 = 0; c0 < NPTS; c0 += 2048) {
        for (int k = 0; k < 2048 / THREADS; ++k) {
            const int j = k * THREADS + threadIdx.x;
            const float* tp = dbB + (size_t)(c0 + j) * 3;
            const float tx = tp[0], ty = tp[1], tz = tp[2];
            lds[j] = make_float4(tx, ty, tz, tx * tx + ty * ty + tz * tz);
        }
        __syncthreads();
        for (int j = 0; j < 2048; ++j) {
            const float4 T = lds[j];
            m0 = fminf(m0, fmaf(npx, T.x, fmaf(npy, T.y, fmaf(npz, T.z, T.w))));
        }
        __syncthreads();
    }
    float v = fmaxf(P + m0, 0.0f);
    #pragma unroll
    for (int off = 32; off > 0; off >>= 1)
        v += __shfl_down(v, off, 64);
    __shared__ float wsum[THREADS / 64];
    if ((threadIdx.x & 63) == 0) wsum[threadIdx.x >> 6] = v;
    __syncthreads();
    if (threadIdx.x == 0)
        atomicAdd(out, (wsum[0] + wsum[1] + wsum[2] + wsum[3]) * inv_count);
}

extern "C" void kernel_launch(void* const* d_in, const int* in_sizes, int n_in,
                              void* d_out, int out_size, void* d_ws, size_t ws_size,
                              hipStream_t stream) {
    const float* pred   = (const float*)d_in[0];
    const float* target = (const float*)d_in[1];
    float* out = (float*)d_out;
    const float inv_count = 1.0f / (float)(BATCH * NPTS);

    if (ws_size >= WS1_BYTES) {
        uint4* enc  = (uint4*)d_ws;
        float* mins = (float*)((char*)d_ws + ENC_BYTES);
        chamfer_encode_kernel<<<(2 * BATCH * NPTS) / THREADS, THREADS, 0, stream>>>(
            pred, target, enc, out);
        chamfer_mfma4_kernel<<<1024, THREADS, 0, stream>>>(pred, target, enc, mins);
        chamfer_finish4_kernel<<<ENTRIES / (THREADS * 4), THREADS, 0, stream>>>(
            mins, out, inv_count);
    } else if (ws_size >= WS_BYTES) {
        hipMemsetAsync(out, 0, out_size * sizeof(float), stream);
        unsigned* ws = (unsigned*)d_ws;
        hipMemsetAsync(ws, 0xFF, WS_BYTES, stream);
        chamfer_mfma_kernel<<<1024, THREADS, 0, stream>>>(pred, target, ws);
        chamfer_finish_kernel<<<ENTRIES / (THREADS * 4), THREADS, 0, stream>>>(ws, out, inv_count);
    } else {
        hipMemsetAsync(out, 0, out_size * sizeof(float), stream);
        dim3 grid(BATCH * (NPTS / THREADS), 2);
        chamfer_fallback_kernel<<<grid, THREADS, 0, stream>>>(pred, target, out, inv_count);
    }
}

// Round 17
// 92.113 us; speedup vs baseline: 4.5524x; 4.5524x over previous
//
#include <hip/hip_runtime.h>
#include <math.h>

#define THREADS  256
#define NPTS     8192
#define BATCH    8
#define ENTRIES  (2 * BATCH * NPTS)                // 131072 per-query slots
#define NPLANES  4
#define MINS_BYTES ((size_t)NPLANES * ENTRIES * 4) // 2 MB tier-1
#define WS_BYTES  ((size_t)ENTRIES * 4)            // 512 KB tier-2

typedef __attribute__((ext_vector_type(8)))  short bf16x8;
typedef __attribute__((ext_vector_type(8)))  float f32x8;
typedef __attribute__((ext_vector_type(16))) float f32x16;

union FragCast { uint4 u; bf16x8 v; };

__device__ __forceinline__ unsigned short f2bf(float f) {
    unsigned u = __float_as_uint(f);
    unsigned r = (u + 0x7FFFu + ((u >> 16) & 1u)) >> 16;   // RNE
    return (unsigned short)r;
}
__device__ __forceinline__ float bf2f(unsigned short h) {
    return __uint_as_float(((unsigned)h) << 16);
}
#define PK(a, b) (((unsigned)(a)) | (((unsigned)(b)) << 16))
#define BF_ONE 0x3F80u

// ---------- encode a db point (x,y,z) into the two 16B K-half rows ----------
__device__ __forceinline__ void encode_db_point(float x, float y, float z,
                                                uint4& h0, uint4& h1) {
    const float sq = fmaf(x, x, fmaf(y, y, z * z));
    const unsigned short xh = f2bf(x), yh = f2bf(y), zh = f2bf(z);
    const unsigned short xl = f2bf(x - bf2f(xh));
    const unsigned short yl = f2bf(y - bf2f(yh));
    const unsigned short zl = f2bf(z - bf2f(zh));
    const unsigned short sh = f2bf(sq);
    const unsigned short sl = f2bf(sq - bf2f(sh));
    h0 = make_uint4(PK(xh, yh), PK(zh, xl), PK(yl, zl), PK(xh, yh));
    h1 = make_uint4(PK(zh, xl), PK(yl, zl), PK(sh, sl), PK(BF_ONE, BF_ONE));
}

// ---------- build a query B-fragment (w = -2q, |q|^2 in k-slots) ----------
__device__ __forceinline__ bf16x8 make_query_frag(const float* qp, int half) {
    const float x = qp[0], y = qp[1], z = qp[2];
    const float sq = fmaf(x, x, fmaf(y, y, z * z));
    const float wx = -2.0f * x, wy = -2.0f * y, wz = -2.0f * z;
    const unsigned short wxh = f2bf(wx), wyh = f2bf(wy), wzh = f2bf(wz);
    const unsigned short wxl = f2bf(wx - bf2f(wxh));
    const unsigned short wyl = f2bf(wy - bf2f(wyh));
    const unsigned short wzl = f2bf(wz - bf2f(wzh));
    const unsigned short sh  = f2bf(sq);
    const unsigned short sl  = f2bf(sq - bf2f(sh));
    FragCast fc;
    if (half == 0) fc.u = make_uint4(PK(wxh, wyh), PK(wzh, wxh), PK(wyh, wzh), PK(wxl, wyl));
    else           fc.u = make_uint4(PK(wzl, wxl), PK(wyl, wzl), PK(BF_ONE, BF_ONE), PK(sh, sl));
    return fc.v;
}

// ================= tier-1: LDS + in-kernel encode (R10 structure) + min3 + 4 frags ===========
// grid bits: ds(2) | qb(4) | b(3) | dir(1) -> 1024 blocks, 4 waves, 4 blk/CU.
// Wave: 4 query-frags (128 q, 512 q/block); block sweeps 2048 db pts (2 LDS chunks).
// Per tile: 1 ds_read_b128 -> 4 MFMA (sequential c, low pressure) -> 32 min3.
__global__ __launch_bounds__(THREADS, 4)
void chamfer_mfma5_kernel(const float* __restrict__ pred,
                          const float* __restrict__ target,
                          float* __restrict__ mins)
{
    __shared__ short lds[32 * 64 * 8];   // 32 KB = one 1024-point chunk image

    const int bx  = blockIdx.x;
    const int ds  = bx & 3;
    const int qb  = (bx >> 2) & 15;
    const int b   = (bx >> 6) & 7;
    const int dir = bx >> 9;

    const float* qarr = dir ? target : pred;
    const float* darr = dir ? pred   : target;

    const int tid  = threadIdx.x;
    const int ln   = tid & 63;
    const int w    = tid >> 6;
    const int half = ln >> 5;

    // ---- 4 query B-fragments (128 queries/wave) ----
    const int qbase = qb * 512 + w * 128;
    const size_t qrow = (size_t)b * NPTS;
    const bf16x8 bq0 = make_query_frag(qarr + (qrow + qbase +  0 + (ln & 31)) * 3, half);
    const bf16x8 bq1 = make_query_frag(qarr + (qrow + qbase + 32 + (ln & 31)) * 3, half);
    const bf16x8 bq2 = make_query_frag(qarr + (qrow + qbase + 64 + (ln & 31)) * 3, half);
    const bf16x8 bq3 = make_query_frag(qarr + (qrow + qbase + 96 + (ln & 31)) * 3, half);

    const f32x16 zacc = {};
    f32x8 m0, m1, m2, m3;
    #pragma unroll
    for (int i = 0; i < 8; ++i) { m0[i] = INFINITY; m1[i] = INFINITY; m2[i] = INFINITY; m3[i] = INFINITY; }

    const int range0 = ds * 2048;

    for (int chunk = 0; chunk < 2; ++chunk) {
        // ---- stage 1024 encoded db points into LDS ----
        #pragma unroll
        for (int it = 0; it < 4; ++it) {
            const int pl = it * THREADS + tid;
            const int p  = range0 + chunk * 1024 + pl;
            const float* tp = darr + ((size_t)b * NPTS + p) * 3;
            uint4 h0, h1;
            encode_db_point(tp[0], tp[1], tp[2], h0, h1);
            const int j = pl >> 5, c = pl & 31;
            *(uint4*)&lds[(j * 64 + c) * 8]      = h0;
            *(uint4*)&lds[(j * 64 + c + 32) * 8] = h1;
        }
        __syncthreads();

        // ---- 32 tiles: 1 ds_read_b128 -> 4 sequential MFMA -> 32 min3 ----
        #pragma unroll 2
        for (int j = 0; j < 32; ++j) {
            const bf16x8 a = *(const bf16x8*)&lds[(j * 64 + ln) * 8];
            {
                const f32x16 c = __builtin_amdgcn_mfma_f32_32x32x16_bf16(a, bq0, zacc, 0, 0, 0);
                #pragma unroll
                for (int i = 0; i < 8; ++i) m0[i] = fminf(fminf(m0[i], c[2*i]), c[2*i+1]);
            }
            {
                const f32x16 c = __builtin_amdgcn_mfma_f32_32x32x16_bf16(a, bq1, zacc, 0, 0, 0);
                #pragma unroll
                for (int i = 0; i < 8; ++i) m1[i] = fminf(fminf(m1[i], c[2*i]), c[2*i+1]);
            }
            {
                const f32x16 c = __builtin_amdgcn_mfma_f32_32x32x16_bf16(a, bq2, zacc, 0, 0, 0);
                #pragma unroll
                for (int i = 0; i < 8; ++i) m2[i] = fminf(fminf(m2[i], c[2*i]), c[2*i+1]);
            }
            {
                const f32x16 c = __builtin_amdgcn_mfma_f32_32x32x16_bf16(a, bq3, zacc, 0, 0, 0);
                #pragma unroll
                for (int i = 0; i < 8; ++i) m3[i] = fminf(fminf(m3[i], c[2*i]), c[2*i+1]);
            }
        }
        __syncthreads();
    }

    // ---- fold 8 -> 1 per frag, cross-half, plain store to ds-plane ----
    const int base = ds * ENTRIES + dir * (BATCH * NPTS) + b * NPTS + qbase;
    #pragma unroll
    for (int nb = 0; nb < 4; ++nb) {
        const f32x8& m = (nb == 0) ? m0 : (nb == 1) ? m1 : (nb == 2) ? m2 : m3;
        float r = fminf(fminf(fminf(m[0], m[1]), fminf(m[2], m[3])),
                        fminf(fminf(m[4], m[5]), fminf(m[6], m[7])));
        r = fminf(r, __shfl_xor(r, 32, 64));
        if (ln < 32) mins[base + nb * 32 + ln] = r;
    }
}

// ---- tier-1 finish: 128 blocks, min 4 planes, clamp, sum, atomicAdd ----
__global__ __launch_bounds__(THREADS)
void chamfer_finish4_kernel(const float* __restrict__ mins,
                            float* __restrict__ out,
                            float inv_count)
{
    const int t = blockIdx.x * THREADS + threadIdx.x;     // 0..32767
    const float4* p0 = (const float4*)mins;
    const float4* p1 = (const float4*)(mins + ENTRIES);
    const float4* p2 = (const float4*)(mins + 2 * ENTRIES);
    const float4* p3 = (const float4*)(mins + 3 * ENTRIES);
    const float4 a = p0[t], c = p1[t], d = p2[t], e = p3[t];
    float s = fmaxf(fminf(fminf(a.x, c.x), fminf(d.x, e.x)), 0.0f)
            + fmaxf(fminf(fminf(a.y, c.y), fminf(d.y, e.y)), 0.0f)
            + fmaxf(fminf(fminf(a.z, c.z), fminf(d.z, e.z)), 0.0f)
            + fmaxf(fminf(fminf(a.w, c.w), fminf(d.w, e.w)), 0.0f);
    float v = s;
    #pragma unroll
    for (int off = 32; off > 0; off >>= 1)
        v += __shfl_down(v, off, 64);
    __shared__ float wsum[THREADS / 64];
    if ((threadIdx.x & 63) == 0) wsum[threadIdx.x >> 6] = v;
    __syncthreads();
    if (threadIdx.x == 0)
        atomicAdd(out, (wsum[0] + wsum[1] + wsum[2] + wsum[3]) * inv_count);
}

// ================= tier-2: atomic-key kernels (ws in [512K, 2M)) =================
__global__ __launch_bounds__(THREADS, 4)
void chamfer_mfma_kernel(const float* __restrict__ pred,
                         const float* __restrict__ target,
                         unsigned* __restrict__ wskeys)
{
    __shared__ short lds[32 * 64 * 8];
    const int bx  = blockIdx.x;
    const int ds  = bx & 3;
    const int qb  = (bx >> 2) & 15;
    const int b   = (bx >> 6) & 7;
    const int dir = bx >> 9;
    const float* qarr = dir ? target : pred;
    const float* darr = dir ? pred   : target;
    const int tid  = threadIdx.x;
    const int ln   = tid & 63;
    const int w    = tid >> 6;
    const int half = ln >> 5;

    bf16x8 bq[4];
    const int qbase = qb * 512 + w * 128;
    #pragma unroll
    for (int nb = 0; nb < 4; ++nb)
        bq[nb] = make_query_frag(qarr + ((size_t)b * NPTS + qbase + nb * 32 + (ln & 31)) * 3, half);

    float mn[4] = {INFINITY, INFINITY, INFINITY, INFINITY};
    const int range0 = ds * 2048;
    for (int chunk = 0; chunk < 2; ++chunk) {
        #pragma unroll
        for (int it = 0; it < 4; ++it) {
            const int pl = it * THREADS + tid;
            const int p  = range0 + chunk * 1024 + pl;
            const float* tp = darr + ((size_t)b * NPTS + p) * 3;
            uint4 h0, h1;
            encode_db_point(tp[0], tp[1], tp[2], h0, h1);
            const int j = pl >> 5, c = pl & 31;
            *(uint4*)&lds[(j * 64 + c) * 8]      = h0;
            *(uint4*)&lds[(j * 64 + c + 32) * 8] = h1;
        }
        __syncthreads();
        #pragma unroll 4
        for (int j = 0; j < 32; ++j) {
            const bf16x8 a = *(const bf16x8*)&lds[(j * 64 + ln) * 8];
            f32x16 z = {};
            f32x16 c0 = __builtin_amdgcn_mfma_f32_32x32x16_bf16(a, bq[0], z, 0, 0, 0);
            f32x16 c1 = __builtin_amdgcn_mfma_f32_32x32x16_bf16(a, bq[1], z, 0, 0, 0);
            f32x16 c2 = __builtin_amdgcn_mfma_f32_32x32x16_bf16(a, bq[2], z, 0, 0, 0);
            f32x16 c3 = __builtin_amdgcn_mfma_f32_32x32x16_bf16(a, bq[3], z, 0, 0, 0);
            #pragma unroll
            for (int i = 0; i < 16; i += 2) {
                mn[0] = fminf(mn[0], fminf(c0[i], c0[i + 1]));
                mn[1] = fminf(mn[1], fminf(c1[i], c1[i + 1]));
                mn[2] = fminf(mn[2], fminf(c2[i], c2[i + 1]));
                mn[3] = fminf(mn[3], fminf(c3[i], c3[i + 1]));
            }
        }
        __syncthreads();
    }
    const int obase = dir * (BATCH * NPTS) + b * NPTS;
    #pragma unroll
    for (int nb = 0; nb < 4; ++nb) {
        const float o = __shfl_xor(mn[nb], 32, 64);
        const float m = fminf(mn[nb], o);
        if (ln < 32) {
            const unsigned u   = __float_as_uint(m);
            const unsigned key = (u >> 31) ? ~u : (u | 0x80000000u);
            atomicMin(&wskeys[obase + qbase + nb * 32 + ln], key);
        }
    }
}

__global__ __launch_bounds__(THREADS)
void chamfer_finish_kernel(const unsigned* __restrict__ ws,
                           float* __restrict__ out,
                           float inv_count)
{
    const int t = blockIdx.x * THREADS + threadIdx.x;
    const uint4 kk = ((const uint4*)ws)[t];
    float s = 0.0f;
    { const unsigned u = (kk.x >> 31) ? (kk.x ^ 0x80000000u) : ~kk.x; s += fmaxf(__uint_as_float(u), 0.0f); }
    { const unsigned u = (kk.y >> 31) ? (kk.y ^ 0x80000000u) : ~kk.y; s += fmaxf(__uint_as_float(u), 0.0f); }
    { const unsigned u = (kk.z >> 31) ? (kk.z ^ 0x80000000u) : ~kk.z; s += fmaxf(__uint_as_float(u), 0.0f); }
    { const unsigned u = (kk.w >> 31) ? (kk.w ^ 0x80000000u) : ~kk.w; s += fmaxf(__uint_as_float(u), 0.0f); }
    float v = s;
    #pragma unroll
    for (int off = 32; off > 0; off >>= 1)
        v += __shfl_down(v, off, 64);
    __shared__ float wsum[THREADS / 64];
    if ((threadIdx.x & 63) == 0) wsum[threadIdx.x >> 6] = v;
    __syncthreads();
    if (threadIdx.x == 0)
        atomicAdd(out, (wsum[0] + wsum[1] + wsum[2] + wsum[3]) * inv_count);
}

// ================= tier-3 fallback =================
__global__ __launch_bounds__(THREADS, 2)
void chamfer_fallback_kernel(const float* __restrict__ pred,
                             const float* __restrict__ target,
                             float* __restrict__ out,
                             float inv_count)
{
    __shared__ float4 lds[2048];
    const float* q  = (blockIdx.y == 0) ? pred   : target;
    const float* db = (blockIdx.y == 0) ? target : pred;
    const int b = blockIdx.x / (NPTS / THREADS);
    const int n = (blockIdx.x % (NPTS / THREADS)) * THREADS + threadIdx.x;
    const float* qp = q + ((size_t)b * NPTS + n) * 3;
    const float px = qp[0], py = qp[1], pz = qp[2];
    const float npx = -2.0f * px, npy = -2.0f * py, npz = -2.0f * pz;
    const float P = px * px + py * py + pz * pz;
    const float* dbB = db + (size_t)b * NPTS * 3;
    float m0 = INFINITY;
    for (int c0 = 0; c0 < NPTS; c0 += 2048) {
        for (int k = 0; k < 2048 / THREADS; ++k) {
            const int j = k * THREADS + threadIdx.x;
            const float* tp = dbB + (size_t)(c0 + j) * 3;
            const float tx = tp[0], ty = tp[1], tz = tp[2];
            lds[j] = make_float4(tx, ty, tz, tx * tx + ty * ty + tz * tz);
        }
        __syncthreads();
        for (int j = 0; j < 2048; ++j) {
            const float4 T = lds[j];
            m0 = fminf(m0, fmaf(npx, T.x, fmaf(npy, T.y, fmaf(npz, T.z, T.w))));
        }
        __syncthreads();
    }
    float v = fmaxf(P + m0, 0.0f);
    #pragma unroll
    for (int off = 32; off > 0; off >>= 1)
        v += __shfl_down(v, off, 64);
    __shared__ float wsum[THREADS / 64];
    if ((threadIdx.x & 63) == 0) wsum[threadIdx.x >> 6] = v;
    __syncthreads();
    if (threadIdx.x == 0)
        atomicAdd(out, (wsum[0] + wsum[1] + wsum[2] + wsum[3]) * inv_count);
}

extern "C" void kernel_launch(void* const* d_in, const int* in_sizes, int n_in,
                              void* d_out, int out_size, void* d_ws, size_t ws_size,
                              hipStream_t stream) {
    const float* pred   = (const float*)d_in[0];
    const float* target = (const float*)d_in[1];
    float* out = (float*)d_out;
    const float inv_count = 1.0f / (float)(BATCH * NPTS);

    if (ws_size >= MINS_BYTES) {
        float* mins = (float*)d_ws;
        hipMemsetAsync(out, 0, out_size * sizeof(float), stream);
        chamfer_mfma5_kernel<<<1024, THREADS, 0, stream>>>(pred, target, mins);
        chamfer_finish4_kernel<<<ENTRIES / (THREADS * 4), THREADS, 0, stream>>>(
            mins, out, inv_count);
    } else if (ws_size >= WS_BYTES) {
        hipMemsetAsync(out, 0, out_size * sizeof(float), stream);
        unsigned* ws = (unsigned*)d_ws;
        hipMemsetAsync(ws, 0xFF, WS_BYTES, stream);
        chamfer_mfma_kernel<<<1024, THREADS, 0, stream>>>(pred, target, ws);
        chamfer_finish_kernel<<<ENTRIES / (THREADS * 4), THREADS, 0, stream>>>(ws, out, inv_count);
    } else {
        hipMemsetAsync(out, 0, out_size * sizeof(float), stream);
        dim3 grid(BATCH * (NPTS / THREADS), 2);
        chamfer_fallback_kernel<<<grid, THREADS, 0, stream>>>(pred, target, out, inv_count);
    }
}